// Round 1
// baseline (2298.692 us; speedup 1.0000x reference)
//
#include <hip/hip_runtime.h>

#define BATCH 2
#define SEQ 1024
#define DM 1024
#define DI 2048
#define DSTATE 16
#define NP (DI + 2*DSTATE)   /* 2080 */
#define ROWS (BATCH*SEQ)     /* 2048 */

__device__ __forceinline__ float softplus_f(float x){
  // jax.nn.softplus = max(x,0) + log1p(exp(-|x|))
  return fmaxf(x, 0.0f) + log1pf(expf(-fabsf(x)));
}

// ---------------------------------------------------------------------------
// Tiled f32 GEMM: C[M,N] = act(A[M,K] @ B[K,N] + bias[N] (+ R[M,N]))
// A row-major lda, B row-major ldb. BM=BN=128, BK=16, 256 thr, 8x8/thread.
// M must be multiple of 128, K multiple of 16; N guarded.
// ACT: 0 = none, 1 = softplus.
// ---------------------------------------------------------------------------
template<int ACT, bool RESID>
__global__ __launch_bounds__(256, 2) void gemm_f32_kernel(
    const float* __restrict__ A, int lda,
    const float* __restrict__ B, int ldb,
    const float* __restrict__ bias,
    const float* __restrict__ R, int ldr,
    float* __restrict__ C, int ldc,
    int M, int N, int K)
{
  constexpr int BM = 128, BN = 128, BK = 16, PADA = 4, PADB = 4;
  __shared__ float As[BK][BM + PADA];
  __shared__ float Bs[BK][BN + PADB];

  const int t  = threadIdx.x;
  const int bm = blockIdx.y * BM;
  const int bn = blockIdx.x * BN;
  const int tm = (t >> 4) << 3;   // 0..120
  const int tn = (t & 15) << 3;   // 0..120

  float acc[8][8];
  #pragma unroll
  for (int i = 0; i < 8; ++i)
    #pragma unroll
    for (int j = 0; j < 8; ++j) acc[i][j] = 0.0f;

  for (int k0 = 0; k0 < K; k0 += BK) {
    // ---- stage A tile (transposed into As[k][m], padded) ----
    #pragma unroll
    for (int j = 0; j < 2; ++j) {
      int f  = t + 256 * j;          // 0..511
      int m  = f >> 2;               // 0..127
      int k4 = (f & 3) << 2;         // 0,4,8,12
      const float* ap = A + (size_t)(bm + m) * lda + (k0 + k4);
      float4 v = *reinterpret_cast<const float4*>(ap);
      As[k4 + 0][m] = v.x;
      As[k4 + 1][m] = v.y;
      As[k4 + 2][m] = v.z;
      As[k4 + 3][m] = v.w;
    }
    // ---- stage B tile (row-major, N-guarded) ----
    #pragma unroll
    for (int j = 0; j < 2; ++j) {
      int f  = t + 256 * j;
      int kk = f >> 5;               // 0..15
      int n4 = (f & 31) << 2;        // 0..124
      int ncol = bn + n4;
      const float* bp = B + (size_t)(k0 + kk) * ldb + ncol;
      float4 v;
      if (ncol + 3 < N) {
        v = *reinterpret_cast<const float4*>(bp);
      } else {
        v.x = (ncol + 0 < N) ? bp[0] : 0.0f;
        v.y = (ncol + 1 < N) ? bp[1] : 0.0f;
        v.z = (ncol + 2 < N) ? bp[2] : 0.0f;
        v.w = (ncol + 3 < N) ? bp[3] : 0.0f;
      }
      *reinterpret_cast<float4*>(&Bs[kk][n4]) = v;
    }
    __syncthreads();

    #pragma unroll
    for (int kk = 0; kk < BK; ++kk) {
      float a[8], b[8];
      *reinterpret_cast<float4*>(&a[0]) = *reinterpret_cast<const float4*>(&As[kk][tm]);
      *reinterpret_cast<float4*>(&a[4]) = *reinterpret_cast<const float4*>(&As[kk][tm + 4]);
      *reinterpret_cast<float4*>(&b[0]) = *reinterpret_cast<const float4*>(&Bs[kk][tn]);
      *reinterpret_cast<float4*>(&b[4]) = *reinterpret_cast<const float4*>(&Bs[kk][tn + 4]);
      #pragma unroll
      for (int i = 0; i < 8; ++i)
        #pragma unroll
        for (int j = 0; j < 8; ++j)
          acc[i][j] = fmaf(a[i], b[j], acc[i][j]);
    }
    __syncthreads();
  }

  // ---- epilogue ----
  #pragma unroll
  for (int i = 0; i < 8; ++i) {
    int r = bm + tm + i;
    #pragma unroll
    for (int j = 0; j < 8; ++j) {
      int c = bn + tn + j;
      if (c < N) {
        float v = acc[i][j] + bias[c];
        if (RESID) v += R[(size_t)r * ldr + c];
        if (ACT == 1) v = softplus_f(v);
        C[(size_t)r * ldc + c] = v;
      }
    }
  }
}

// ---------------------------------------------------------------------------
// Causal depthwise conv (D_CONV=4) over time + heaviside spike.
// x_in = xr[:, 0:DI] (row stride 2*DI). spikes[row, c] in {0,1}.
// ---------------------------------------------------------------------------
__global__ __launch_bounds__(256) void conv_spike_kernel(
    const float* __restrict__ xr, const float* __restrict__ W_conv,
    const float* __restrict__ b_conv, float* __restrict__ spikes)
{
  int g   = blockIdx.x * 256 + threadIdx.x;     // [0, ROWS*DI)
  int c   = g & (DI - 1);
  int row = g >> 11;                            // 0..2047
  int t   = row & (SEQ - 1);

  float4 wc = reinterpret_cast<const float4*>(W_conv)[c];
  float w[4] = { wc.x, wc.y, wc.z, wc.w };
  float v = b_conv[c];
  #pragma unroll
  for (int k = 0; k < 4; ++k) {
    int tt = t - 3 + k;   // weight k multiplies x at time t-3+k (left pad)
    if (tt >= 0) {
      float xv = xr[(size_t)(row - 3 + k) * (2 * DI) + c];
      v = fmaf(xv, w[k], v);
    }
  }
  spikes[(size_t)row * DI + c] = (v >= 1.0f) ? 1.0f : 0.0f;
}

// ---------------------------------------------------------------------------
// Selective scan, one thread per (b, d, s). 16 lanes per channel reduce h*C
// via width-16 shuffles; lane s==0 applies +spk*D and the SiLU gate and
// writes y into the (consumed) delta_pre columns of params (stride NP).
// ---------------------------------------------------------------------------
__global__ __launch_bounds__(256) void scan_kernel(
    const float* __restrict__ delta,   // [ROWS, DI]
    const float* __restrict__ spikes,  // [ROWS, DI]
    const float* __restrict__ bc,      // params + DI : Bp at [row*NP + s], Cp at +16
    const float* __restrict__ xr,      // res = xr[row*(2*DI) + DI + d]
    const float* __restrict__ A_log,   // [DI, 16]
    const float* __restrict__ D_param, // [DI]
    float* __restrict__ yout)          // params base; write [row*NP + d]
{
  int g  = blockIdx.x * 256 + threadIdx.x;  // [0, BATCH*DI*16)
  int s  = g & 15;
  int ch = g >> 4;            // 0..4095
  int d  = ch & (DI - 1);
  int b  = ch >> 11;

  float A_s = -expf(A_log[(size_t)d * DSTATE + s]);
  float Dp  = D_param[d];

  size_t baseRow = (size_t)b * SEQ;
  const float* pD = delta  + baseRow * DI + d;
  const float* pS = spikes + baseRow * DI + d;
  const float* pB = bc     + baseRow * NP + s;
  const float* pC = pB + DSTATE;
  const float* pR = xr     + baseRow * (2 * DI) + DI + d;
  float*       pY = yout   + baseRow * NP + d;

  float h = 0.0f;
  for (int t = 0; t < SEQ; ++t) {
    float dl = *pD;
    float sp = *pS;
    float Bp = *pB;
    float Cp = *pC;
    float Ab = expf(dl * A_s);
    h = fmaf(Ab, h, (dl * sp) * Bp);
    float v = h * Cp;
    v += __shfl_xor(v, 1, 16);
    v += __shfl_xor(v, 2, 16);
    v += __shfl_xor(v, 4, 16);
    v += __shfl_xor(v, 8, 16);
    if (s == 0) {
      float r   = *pR;
      float sig = 1.0f / (1.0f + expf(-r));
      *pY = (v + sp * Dp) * (r * sig);
    }
    pD += DI; pS += DI; pB += NP; pC += NP; pR += 2 * DI; pY += NP;
  }
}

// ---------------------------------------------------------------------------
// Row LayerNorm (two-pass) + final heaviside spike. One block per row.
// ---------------------------------------------------------------------------
__global__ __launch_bounds__(256) void ln_spike_kernel(
    const float* __restrict__ o, const float* __restrict__ gamma,
    const float* __restrict__ beta, float* __restrict__ out)
{
  const int row = blockIdx.x;
  const int tid = threadIdx.x;
  const float* orow = o + (size_t)row * DM;

  float vals[4];
  float sum = 0.0f;
  #pragma unroll
  for (int j = 0; j < 4; ++j) { vals[j] = orow[tid + 256 * j]; sum += vals[j]; }
  #pragma unroll
  for (int off = 1; off < 64; off <<= 1) sum += __shfl_xor(sum, off, 64);

  __shared__ float ws4[4];
  const int wid = tid >> 6, lane = tid & 63;
  if (lane == 0) ws4[wid] = sum;
  __syncthreads();
  float mu = (ws4[0] + ws4[1] + ws4[2] + ws4[3]) * (1.0f / DM);

  float vs = 0.0f;
  #pragma unroll
  for (int j = 0; j < 4; ++j) { float dv = vals[j] - mu; vs += dv * dv; }
  #pragma unroll
  for (int off = 1; off < 64; off <<= 1) vs += __shfl_xor(vs, off, 64);
  __syncthreads();
  if (lane == 0) ws4[wid] = vs;
  __syncthreads();
  float var = (ws4[0] + ws4[1] + ws4[2] + ws4[3]) * (1.0f / DM);
  float inv = 1.0f / sqrtf(var + 1e-5f);

  float* outrow = out + (size_t)row * DM;
  #pragma unroll
  for (int j = 0; j < 4; ++j) {
    int c = tid + 256 * j;
    float nv = fmaf((vals[j] - mu) * inv, gamma[c], beta[c]);
    outrow[c] = (nv >= 1.0f) ? 1.0f : 0.0f;
  }
}

// ---------------------------------------------------------------------------
extern "C" void kernel_launch(void* const* d_in, const int* in_sizes, int n_in,
                              void* d_out, int out_size, void* d_ws, size_t ws_size,
                              hipStream_t stream) {
  const float* x      = (const float*)d_in[0];
  const float* W_in   = (const float*)d_in[1];
  const float* b_in   = (const float*)d_in[2];
  const float* W_conv = (const float*)d_in[3];
  const float* b_conv = (const float*)d_in[4];
  const float* W_x    = (const float*)d_in[5];
  const float* b_x    = (const float*)d_in[6];
  const float* W_dt   = (const float*)d_in[7];
  const float* b_dt   = (const float*)d_in[8];
  const float* A_log  = (const float*)d_in[9];
  const float* D_par  = (const float*)d_in[10];
  const float* W_out  = (const float*)d_in[11];
  const float* b_out  = (const float*)d_in[12];
  const float* gamma  = (const float*)d_in[13];
  const float* beta   = (const float*)d_in[14];
  float* out = (float*)d_out;

  // workspace layout (floats)
  float* ws     = (float*)d_ws;
  float* xr     = ws;                                  // [ROWS, 2*DI]  33.55 MB
  float* spikes = xr     + (size_t)ROWS * (2 * DI);    // [ROWS, DI]    16.78 MB
  float* params = spikes + (size_t)ROWS * DI;          // [ROWS, NP]    17.04 MB
  float* delta  = params + (size_t)ROWS * NP;          // [ROWS, DI]    16.78 MB
  float* o      = spikes;  // spikes dead after scan; o is [ROWS, DM]

  dim3 blk(256);

  // G1: xr = x @ W_in + b_in                       [2048 x 4096, K=1024]
  gemm_f32_kernel<0, false><<<dim3(32, 16), blk, 0, stream>>>(
      x, DM, W_in, 2 * DI, b_in, nullptr, 0, xr, 2 * DI, ROWS, 2 * DI, DM);

  // conv + spike
  conv_spike_kernel<<<(ROWS * DI) / 256, blk, 0, stream>>>(xr, W_conv, b_conv, spikes);

  // G2: params = spikes @ W_x + b_x                [2048 x 2080, K=2048]
  gemm_f32_kernel<0, false><<<dim3(17, 16), blk, 0, stream>>>(
      spikes, DI, W_x, NP, b_x, nullptr, 0, params, NP, ROWS, NP, DI);

  // G3: delta = softplus(delta_pre @ W_dt + b_dt)  [2048 x 2048, K=2048]
  gemm_f32_kernel<1, false><<<dim3(16, 16), blk, 0, stream>>>(
      params, NP, W_dt, DI, b_dt, nullptr, 0, delta, DI, ROWS, DI, DI);

  // scan (+ D skip + SiLU gate); writes y into params cols [0, DI)
  scan_kernel<<<(BATCH * DI * DSTATE) / 256, blk, 0, stream>>>(
      delta, spikes, params + DI, xr, A_log, D_par, params);

  // G4: o = x + y @ W_out + b_out                  [2048 x 1024, K=2048]
  gemm_f32_kernel<0, true><<<dim3(8, 16), blk, 0, stream>>>(
      params, NP, W_out, DM, b_out, x, DM, o, DM, ROWS, DM, DI);

  // LayerNorm + spike -> out
  ln_spike_kernel<<<ROWS, blk, 0, stream>>>(o, gamma, beta, out);
}

// Round 2
// 1498.181 us; speedup vs baseline: 1.5343x; 1.5343x over previous
//
#include <hip/hip_runtime.h>

#define BATCH 2
#define SEQ 1024
#define DM 1024
#define DI 2048
#define DSTATE 16
#define NP (DI + 2*DSTATE)   /* 2080 */
#define ROWS (BATCH*SEQ)     /* 2048 */
#define NCH 16               /* scan chunks */
#define CHT (SEQ/NCH)        /* 64 timesteps per chunk */
#define CSZ (BATCH*DI*DSTATE) /* 65536 recurrences */

__device__ __forceinline__ float softplus_f(float x){
  return fmaxf(x, 0.0f) + log1pf(expf(-fabsf(x)));
}

// ---------------------------------------------------------------------------
// Tiled f32 GEMM with register-prefetch pipeline.
// C[M,N] = act(A[M,K] @ B[K,N] + bias[N] (+ R[M,N]))
// BM=BN=128, BK=16, 256 thr, 8x8/thread. M %128==0, K %16==0; N guarded.
// ---------------------------------------------------------------------------
template<int ACT, bool RESID>
__global__ __launch_bounds__(256, 2) void gemm_f32_kernel(
    const float* __restrict__ A, int lda,
    const float* __restrict__ B, int ldb,
    const float* __restrict__ bias,
    const float* __restrict__ R, int ldr,
    float* __restrict__ C, int ldc,
    int M, int N, int K)
{
  constexpr int BM = 128, BN = 128, BK = 16;
  __shared__ float As[BK][BM + 4];
  __shared__ float Bs[BK][BN + 4];

  const int t  = threadIdx.x;
  const int bm = blockIdx.y * BM;
  const int bn = blockIdx.x * BN;
  const int tm = (t >> 4) << 3;
  const int tn = (t & 15) << 3;

  float4 va[2], vb[2];

  auto LOAD = [&](int k0) {
    #pragma unroll
    for (int j = 0; j < 2; ++j) {
      int f  = t + 256 * j;
      int m  = f >> 2;
      int k4 = (f & 3) << 2;
      va[j] = *reinterpret_cast<const float4*>(A + (size_t)(bm + m) * lda + (k0 + k4));
      int kk = f >> 5;
      int n4 = (f & 31) << 2;
      int ncol = bn + n4;
      const float* bp = B + (size_t)(k0 + kk) * ldb + ncol;
      float4 v;
      if (ncol + 3 < N) {
        v = *reinterpret_cast<const float4*>(bp);
      } else {
        v.x = (ncol + 0 < N) ? bp[0] : 0.0f;
        v.y = (ncol + 1 < N) ? bp[1] : 0.0f;
        v.z = (ncol + 2 < N) ? bp[2] : 0.0f;
        v.w = (ncol + 3 < N) ? bp[3] : 0.0f;
      }
      vb[j] = v;
    }
  };
  auto STORE = [&]() {
    #pragma unroll
    for (int j = 0; j < 2; ++j) {
      int f  = t + 256 * j;
      int m  = f >> 2;
      int k4 = (f & 3) << 2;
      As[k4 + 0][m] = va[j].x;
      As[k4 + 1][m] = va[j].y;
      As[k4 + 2][m] = va[j].z;
      As[k4 + 3][m] = va[j].w;
      int kk = f >> 5;
      int n4 = (f & 31) << 2;
      *reinterpret_cast<float4*>(&Bs[kk][n4]) = vb[j];
    }
  };

  float acc[8][8];
  #pragma unroll
  for (int i = 0; i < 8; ++i)
    #pragma unroll
    for (int j = 0; j < 8; ++j) acc[i][j] = 0.0f;

  LOAD(0); STORE(); __syncthreads();

  for (int k0 = 0;;) {
    const bool more = (k0 + BK) < K;
    if (more) LOAD(k0 + BK);           // prefetch next tile into regs

    #pragma unroll
    for (int kk = 0; kk < BK; ++kk) {
      float a[8], b[8];
      *reinterpret_cast<float4*>(&a[0]) = *reinterpret_cast<const float4*>(&As[kk][tm]);
      *reinterpret_cast<float4*>(&a[4]) = *reinterpret_cast<const float4*>(&As[kk][tm + 4]);
      *reinterpret_cast<float4*>(&b[0]) = *reinterpret_cast<const float4*>(&Bs[kk][tn]);
      *reinterpret_cast<float4*>(&b[4]) = *reinterpret_cast<const float4*>(&Bs[kk][tn + 4]);
      #pragma unroll
      for (int i = 0; i < 8; ++i)
        #pragma unroll
        for (int j = 0; j < 8; ++j)
          acc[i][j] = fmaf(a[i], b[j], acc[i][j]);
    }
    if (!more) break;
    __syncthreads();
    STORE();
    __syncthreads();
    k0 += BK;
  }

  #pragma unroll
  for (int i = 0; i < 8; ++i) {
    int r = bm + tm + i;
    #pragma unroll
    for (int j = 0; j < 8; ++j) {
      int c = bn + tn + j;
      if (c < N) {
        float v = acc[i][j] + bias[c];
        if (RESID) v += R[(size_t)r * ldr + c];
        if (ACT == 1) v = softplus_f(v);
        C[(size_t)r * ldc + c] = v;
      }
    }
  }
}

// ---------------------------------------------------------------------------
// Causal depthwise conv (D_CONV=4) + heaviside spike.
// ---------------------------------------------------------------------------
__global__ __launch_bounds__(256) void conv_spike_kernel(
    const float* __restrict__ xr, const float* __restrict__ W_conv,
    const float* __restrict__ b_conv, float* __restrict__ spikes)
{
  int g   = blockIdx.x * 256 + threadIdx.x;
  int c   = g & (DI - 1);
  int row = g >> 11;
  int t   = row & (SEQ - 1);

  float4 wc = reinterpret_cast<const float4*>(W_conv)[c];
  float w[4] = { wc.x, wc.y, wc.z, wc.w };
  float v = b_conv[c];
  #pragma unroll
  for (int k = 0; k < 4; ++k) {
    int tt = t - 3 + k;
    if (tt >= 0) {
      float xv = xr[(size_t)(row - 3 + k) * (2 * DI) + c];
      v = fmaf(xv, w[k], v);
    }
  }
  spikes[(size_t)row * DI + c] = (v >= 1.0f) ? 1.0f : 0.0f;
}

// ---------------------------------------------------------------------------
// Chunked selective scan. g bit layout: (c, b, d, s) = (g>>16, (g>>15)&1,
// (g>>4)&2047, g&15). Lanes 0..15 of a wave share (c,b,d).
// ---------------------------------------------------------------------------
__global__ __launch_bounds__(256) void scan_pass1(
    const float* __restrict__ delta, const float* __restrict__ spikes,
    const float* __restrict__ bc, const float* __restrict__ A_log,
    float* __restrict__ hpart, float* __restrict__ Ppart)
{
  int g = blockIdx.x * 256 + threadIdx.x;
  int s = g & 15;
  int d = (g >> 4) & (DI - 1);
  int b = (g >> 15) & (BATCH - 1);
  int c = g >> 16;

  float A_s = -expf(A_log[(size_t)d * DSTATE + s]);
  size_t row0 = (size_t)b * SEQ + c * CHT;
  const float* pD = delta  + row0 * DI + d;
  const float* pS = spikes + row0 * DI + d;
  const float* pB = bc     + row0 * NP + s;

  float h = 0.0f, P = 1.0f;
  for (int t = 0; t < CHT; ++t) {
    float dl = *pD, sp = *pS, Bp = *pB;
    float a = expf(dl * A_s);
    h = fmaf(a, h, (dl * sp) * Bp);
    P *= a;
    pD += DI; pS += DI; pB += NP;
  }
  hpart[g] = h;
  Ppart[g] = P;
}

__global__ __launch_bounds__(256) void scan_combine(
    const float* __restrict__ hpart, const float* __restrict__ Ppart,
    float* __restrict__ init)
{
  int q = blockIdx.x * 256 + threadIdx.x;   // [0, CSZ)
  float H = 0.0f;
  #pragma unroll
  for (int c = 0; c < NCH; ++c) {
    init[c * CSZ + q] = H;
    H = fmaf(Ppart[c * CSZ + q], H, hpart[c * CSZ + q]);
  }
}

__global__ __launch_bounds__(256) void scan_pass2(
    const float* __restrict__ delta, const float* __restrict__ spikes,
    const float* __restrict__ bc, const float* __restrict__ xr,
    const float* __restrict__ A_log, const float* __restrict__ D_param,
    const float* __restrict__ init, float* __restrict__ yout)
{
  int g = blockIdx.x * 256 + threadIdx.x;
  int s = g & 15;
  int d = (g >> 4) & (DI - 1);
  int b = (g >> 15) & (BATCH - 1);
  int c = g >> 16;

  float A_s = -expf(A_log[(size_t)d * DSTATE + s]);
  float Dp  = D_param[d];
  size_t row0 = (size_t)b * SEQ + c * CHT;
  const float* pD = delta  + row0 * DI + d;
  const float* pS = spikes + row0 * DI + d;
  const float* pB = bc     + row0 * NP + s;
  const float* pC = pB + DSTATE;
  const float* pR = xr     + row0 * (2 * DI) + DI + d;
  float*       pY = yout   + row0 * NP + d;

  float h = init[g];
  for (int t = 0; t < CHT; ++t) {
    float dl = *pD, sp = *pS, Bp = *pB, Cp = *pC;
    float a = expf(dl * A_s);
    h = fmaf(a, h, (dl * sp) * Bp);
    float v = h * Cp;
    v += __shfl_xor(v, 1, 16);
    v += __shfl_xor(v, 2, 16);
    v += __shfl_xor(v, 4, 16);
    v += __shfl_xor(v, 8, 16);
    if (s == 0) {
      float r   = *pR;
      float sig = 1.0f / (1.0f + expf(-r));
      *pY = (v + sp * Dp) * (r * sig);
    }
    pD += DI; pS += DI; pB += NP; pC += NP; pR += 2 * DI; pY += NP;
  }
}

// ---------------------------------------------------------------------------
// Row LayerNorm + final spike.
// ---------------------------------------------------------------------------
__global__ __launch_bounds__(256) void ln_spike_kernel(
    const float* __restrict__ o, const float* __restrict__ gamma,
    const float* __restrict__ beta, float* __restrict__ out)
{
  const int row = blockIdx.x;
  const int tid = threadIdx.x;
  const float* orow = o + (size_t)row * DM;

  float vals[4];
  float sum = 0.0f;
  #pragma unroll
  for (int j = 0; j < 4; ++j) { vals[j] = orow[tid + 256 * j]; sum += vals[j]; }
  #pragma unroll
  for (int off = 1; off < 64; off <<= 1) sum += __shfl_xor(sum, off, 64);

  __shared__ float ws4[4];
  const int wid = tid >> 6, lane = tid & 63;
  if (lane == 0) ws4[wid] = sum;
  __syncthreads();
  float mu = (ws4[0] + ws4[1] + ws4[2] + ws4[3]) * (1.0f / DM);

  float vs = 0.0f;
  #pragma unroll
  for (int j = 0; j < 4; ++j) { float dv = vals[j] - mu; vs += dv * dv; }
  #pragma unroll
  for (int off = 1; off < 64; off <<= 1) vs += __shfl_xor(vs, off, 64);
  __syncthreads();
  if (lane == 0) ws4[wid] = vs;
  __syncthreads();
  float var = (ws4[0] + ws4[1] + ws4[2] + ws4[3]) * (1.0f / DM);
  float inv = 1.0f / sqrtf(var + 1e-5f);

  float* outrow = out + (size_t)row * DM;
  #pragma unroll
  for (int j = 0; j < 4; ++j) {
    int c = tid + 256 * j;
    float nv = fmaf((vals[j] - mu) * inv, gamma[c], beta[c]);
    outrow[c] = (nv >= 1.0f) ? 1.0f : 0.0f;
  }
}

// ---------------------------------------------------------------------------
extern "C" void kernel_launch(void* const* d_in, const int* in_sizes, int n_in,
                              void* d_out, int out_size, void* d_ws, size_t ws_size,
                              hipStream_t stream) {
  const float* x      = (const float*)d_in[0];
  const float* W_in   = (const float*)d_in[1];
  const float* b_in   = (const float*)d_in[2];
  const float* W_conv = (const float*)d_in[3];
  const float* b_conv = (const float*)d_in[4];
  const float* W_x    = (const float*)d_in[5];
  const float* b_x    = (const float*)d_in[6];
  const float* W_dt   = (const float*)d_in[7];
  const float* b_dt   = (const float*)d_in[8];
  const float* A_log  = (const float*)d_in[9];
  const float* D_par  = (const float*)d_in[10];
  const float* W_out  = (const float*)d_in[11];
  const float* b_out  = (const float*)d_in[12];
  const float* gamma  = (const float*)d_in[13];
  const float* beta   = (const float*)d_in[14];
  float* out = (float*)d_out;

  // workspace layout (floats)
  float* ws     = (float*)d_ws;
  float* xr     = ws;                                  // [ROWS, 2*DI]
  float* spikes = xr     + (size_t)ROWS * (2 * DI);    // [ROWS, DI]
  float* params = spikes + (size_t)ROWS * DI;          // [ROWS, NP]
  float* delta  = params + (size_t)ROWS * NP;          // [ROWS, DI]
  float* hpart  = delta  + (size_t)ROWS * DI;          // [NCH*CSZ]
  float* Ppart  = hpart  + (size_t)NCH * CSZ;          // [NCH*CSZ]
  float* init   = Ppart  + (size_t)NCH * CSZ;          // [NCH*CSZ]
  float* o      = spikes;  // spikes dead after scan

  dim3 blk(256);

  // G1: xr = x @ W_in + b_in                       [2048 x 4096, K=1024]
  gemm_f32_kernel<0, false><<<dim3(32, 16), blk, 0, stream>>>(
      x, DM, W_in, 2 * DI, b_in, nullptr, 0, xr, 2 * DI, ROWS, 2 * DI, DM);

  // conv + spike
  conv_spike_kernel<<<(ROWS * DI) / 256, blk, 0, stream>>>(xr, W_conv, b_conv, spikes);

  // G2: params = spikes @ W_x + b_x                [2048 x 2080, K=2048]
  gemm_f32_kernel<0, false><<<dim3(17, 16), blk, 0, stream>>>(
      spikes, DI, W_x, NP, b_x, nullptr, 0, params, NP, ROWS, NP, DI);

  // G3: delta = softplus(delta_pre @ W_dt + b_dt)  [2048 x 2048, K=2048]
  gemm_f32_kernel<1, false><<<dim3(16, 16), blk, 0, stream>>>(
      params, NP, W_dt, DI, b_dt, nullptr, 0, delta, DI, ROWS, DI, DI);

  // chunked selective scan (+ D skip + SiLU gate); y into params cols [0,DI)
  scan_pass1<<<(NCH * CSZ) / 256, blk, 0, stream>>>(
      delta, spikes, params + DI, A_log, hpart, Ppart);
  scan_combine<<<CSZ / 256, blk, 0, stream>>>(hpart, Ppart, init);
  scan_pass2<<<(NCH * CSZ) / 256, blk, 0, stream>>>(
      delta, spikes, params + DI, xr, A_log, D_par, init, params);

  // G4: o = x + y @ W_out + b_out                  [2048 x 1024, K=2048]
  gemm_f32_kernel<0, true><<<dim3(8, 16), blk, 0, stream>>>(
      params, NP, W_out, DM, b_out, x, DM, o, DM, ROWS, DM, DI);

  // LayerNorm + spike -> out
  ln_spike_kernel<<<ROWS, blk, 0, stream>>>(o, gamma, beta, out);
}